// Round 1
// baseline (264.764 us; speedup 1.0000x reference)
//
#include <hip/hip_runtime.h>
#include <stdint.h>

typedef unsigned long long u64;
typedef unsigned int u32;

#define CONF_T 0.9f
#define IOU_T 0.5f
#define TOPK 4096
#define SORTN 8192

// ---- workspace layout (bytes) ----
#define HIST_OFF    0          // u32[4096]            16384
#define CTR_OFF     16384      // u32[16]: [0]=cnt2 [1]=thrB
#define ROWANY_OFF  16448      // u32[4096]            16384
#define SORT_OFF    32832      // u64[8192]            65536
#define MEMSET_BYTES 98368     // zero everything above each call
#define SELBOX_OFF  98368      // float4[4096]         65536
#define SELSC_OFF   163904     // float[4096]          16384
#define SELLM_OFF   180288     // float[4096*10]       163840
#define MASK_OFF    344128     // u64[4096*64]         2097152
#define KEEP_OFF    2441280    // u64[64]              512

__device__ __forceinline__ int score_bin(float s) {
    u32 b = __float_as_uint(s);
    if (b >= 0x3F800000u) return 0;
    int bin = (int)((0x3F800000u - b) >> 9);
    return bin > 4095 ? 4095 : bin;
}

// K1: histogram of candidate scores (score > 0.9)
__global__ void k_hist(const float2* __restrict__ conf, int N, u32* __restrict__ hist) {
    int stride = gridDim.x * blockDim.x;
    for (int i = blockIdx.x * blockDim.x + threadIdx.x; i < N; i += stride) {
        float s = conf[i].y;
        if (s > CONF_T) atomicAdd(&hist[score_bin(s)], 1u);
    }
}

// K2: find threshold bin B such that cum count over bins 0..B first reaches min(total, 4096)
__global__ void k_scan(const u32* __restrict__ hist, u32* __restrict__ ctr) {
    int t = threadIdx.x;  // 64 lanes
    u32 local = 0;
    for (int i = 0; i < 64; i++) local += hist[t * 64 + i];
    u32 incl = local;
    for (int d = 1; d < 64; d <<= 1) {
        u32 v = __shfl_up(incl, d);
        if (t >= d) incl += v;
    }
    u32 excl = incl - local;
    u32 total = __shfl(incl, 63);
    u32 target = total < TOPK ? total : TOPK;
    if (total == 0) {
        if (t == 0) ctr[1] = 4095u;
        return;
    }
    bool has = (excl < target) && (incl >= target);
    if (has) {
        u32 run = excl;
        int B = 4095;
        for (int i = 0; i < 64; i++) {
            run += hist[t * 64 + i];
            if (run >= target) { B = t * 64 + i; break; }
        }
        ctr[1] = (u32)B;
    }
}

// K3: compact superset (bin <= B) as sort keys (score_bits<<32)|~idx
__global__ void k_compact(const float2* __restrict__ conf, int N,
                          const u32* __restrict__ ctr, u32* __restrict__ cnt2,
                          u64* __restrict__ sortbuf) {
    int B = (int)ctr[1];
    int stride = gridDim.x * blockDim.x;
    for (int i = blockIdx.x * blockDim.x + threadIdx.x; i < N; i += stride) {
        float s = conf[i].y;
        if (s > CONF_T && score_bin(s) <= B) {
            u32 pos = atomicAdd(cnt2, 1u);
            if (pos < SORTN) {
                sortbuf[pos] = ((u64)__float_as_uint(s) << 32) | (u64)(~(u32)i);
            }
        }
    }
}

// K4: single-block bitonic sort (descending) of 8192 keys, then decode top-4096
__global__ void __launch_bounds__(1024) k_sort_decode(
        const float4* __restrict__ loc, const float4* __restrict__ priors,
        const float* __restrict__ landm, const u64* __restrict__ sortbuf,
        float4* __restrict__ selbox, float* __restrict__ selscore,
        float* __restrict__ sellm) {
    __shared__ u64 keys[SORTN];
    int t = threadIdx.x;
    for (int i = t; i < SORTN; i += 1024) keys[i] = sortbuf[i];
    __syncthreads();
    for (int k = 2; k <= SORTN; k <<= 1) {
        for (int j = k >> 1; j > 0; j >>= 1) {
            for (int p = t; p < SORTN / 2; p += 1024) {
                int i = ((p & ~(j - 1)) << 1) | (p & (j - 1));
                int l = i | j;
                u64 a = keys[i], b = keys[l];
                bool up = (i & k) == 0;   // descending sort
                if ((a < b) == up) { keys[i] = b; keys[l] = a; }
            }
            __syncthreads();
        }
    }
    for (int p = t; p < TOPK; p += 1024) {
        u64 key = keys[p];
        float4 bx = make_float4(0.f, 0.f, 0.f, 0.f);
        float sc = 0.f;
        float lm[10];
        #pragma unroll
        for (int q = 0; q < 10; q++) lm[q] = 0.f;
        if (key != 0ull) {
            u32 idx = ~(u32)key;
            sc = __uint_as_float((u32)(key >> 32));
            float4 L = loc[idx];
            float4 P = priors[idx];
            float cx = P.x + L.x * 0.1f * P.z;
            float cy = P.y + L.y * 0.1f * P.w;
            float wx = P.z * expf(L.z * 0.2f);
            float wy = P.w * expf(L.w * 0.2f);
            bx.x = (cx - 0.5f * wx) * 8192.f;
            bx.y = (cy - 0.5f * wy) * 8192.f;
            bx.z = (cx + 0.5f * wx) * 8192.f;
            bx.w = (cy + 0.5f * wy) * 8192.f;
            const float* lmr = landm + (size_t)idx * 10;
            #pragma unroll
            for (int q = 0; q < 5; q++) {
                float lx = lmr[2 * q], ly = lmr[2 * q + 1];
                lm[2 * q]     = (P.x + lx * 0.1f * P.z) * 8192.f;
                lm[2 * q + 1] = (P.y + ly * 0.1f * P.w) * 8192.f;
            }
        }
        selbox[p] = bx;
        selscore[p] = sc;
        #pragma unroll
        for (int q = 0; q < 10; q++) sellm[(size_t)p * 10 + q] = lm[q];
    }
}

// K5: suppression bitmask matrix: mask[i][w] bit jj set iff j=w*64+jj > i and IoU(i,j) > 0.5
__global__ void __launch_bounds__(256) k_mask(const float4* __restrict__ selbox,
                                              u64* __restrict__ mask,
                                              u32* __restrict__ rowAny) {
    __shared__ float4 sb[TOPK];   // 64 KB
    int t = threadIdx.x, b = blockIdx.x;
    for (int i = t; i < TOPK; i += 256) sb[i] = selbox[i];
    __syncthreads();
    int row0 = b * 16;
    #pragma unroll
    for (int pp = 0; pp < 4; pp++) {
        int id = t + pp * 256;          // 0..1023
        int row = row0 + (id >> 6);
        int w = id & 63;
        u64 bits = 0ull;
        if (w * 64 + 63 > row) {
            float4 bi = sb[row];
            float ai = fmaxf(bi.z - bi.x, 0.f) * fmaxf(bi.w - bi.y, 0.f);
            int jbase = w * 64;
            for (int jj = 0; jj < 64; jj++) {
                int j = jbase + jj;
                if (j <= row) continue;
                float4 bj = sb[j];
                float aj = fmaxf(bj.z - bj.x, 0.f) * fmaxf(bj.w - bj.y, 0.f);
                float lx = fmaxf(bi.x, bj.x), ly = fmaxf(bi.y, bj.y);
                float rx = fminf(bi.z, bj.z), ry = fminf(bi.w, bj.w);
                float inter = fmaxf(rx - lx, 0.f) * fmaxf(ry - ly, 0.f);
                float iou = inter / (ai + aj - inter + 1e-12f);
                if (iou > IOU_T) bits |= 1ull << jj;
            }
        }
        mask[(size_t)row * 64 + w] = bits;
        if (bits) atomicOr(&rowAny[row], 1u);
    }
}

// K6: serial greedy NMS reduce, one wave, 64-box groups with sparsity skip
__global__ void k_nms(const u64* __restrict__ mask, const u32* __restrict__ rowAny,
                      const float* __restrict__ selscore, u64* __restrict__ keepout) {
    int t = threadIdx.x;  // 64
    u64 sup = 0ull, keepw = 0ull;
    for (int g = 0; g < 64; g++) {
        u64 cur = __shfl(sup, g);
        float sc = selscore[g * 64 + t];
        u64 validw = __ballot(sc > CONF_T);
        u32 ra = rowAny[g * 64 + t];
        u64 nz = __ballot(ra != 0u);
        u64 alive = (~cur) & validw;
        if (nz) {
            u64 intra = mask[(size_t)(g * 64 + t) * 64 + g];
            u64 rem = nz;
            while (rem) {
                int bb = __ffsll(rem) - 1;
                rem &= rem - 1;
                if ((alive >> bb) & 1ull) {
                    u64 rowb = __shfl(intra, bb);
                    alive &= ~rowb;
                }
            }
        }
        if (t == g) keepw = alive;
        u64 srem = alive & nz;
        while (srem) {
            int bb = __ffsll(srem) - 1;
            srem &= srem - 1;
            sup |= mask[(size_t)(g * 64 + bb) * 64 + t];
        }
    }
    keepout[t] = keepw;
}

// K7: write output rows (zeroed when not kept)
__global__ void k_final(const float4* __restrict__ selbox, const float* __restrict__ selscore,
                        const float* __restrict__ sellm, const u64* __restrict__ keep,
                        float* __restrict__ out) {
    int i = blockIdx.x * blockDim.x + threadIdx.x;
    if (i >= TOPK) return;
    bool kp = (keep[i >> 6] >> (i & 63)) & 1ull;
    float4 b = selbox[i];
    float* o = out + (size_t)i * 15;
    o[0] = kp ? b.x : 0.f;
    o[1] = kp ? b.y : 0.f;
    o[2] = kp ? b.z : 0.f;
    o[3] = kp ? b.w : 0.f;
    o[4] = kp ? selscore[i] : 0.f;
    #pragma unroll
    for (int q = 0; q < 10; q++) o[5 + q] = kp ? sellm[(size_t)i * 10 + q] : 0.f;
}

extern "C" void kernel_launch(void* const* d_in, const int* in_sizes, int n_in,
                              void* d_out, int out_size, void* d_ws, size_t ws_size,
                              hipStream_t stream) {
    const float4* loc    = (const float4*)d_in[0];
    const float2* conf   = (const float2*)d_in[1];
    const float*  landm  = (const float*)d_in[2];
    const float4* priors = (const float4*)d_in[3];
    float* out = (float*)d_out;
    int N = in_sizes[1] / 2;

    char* ws = (char*)d_ws;
    u32* hist    = (u32*)(ws + HIST_OFF);
    u32* ctr     = (u32*)(ws + CTR_OFF);
    u32* rowAny  = (u32*)(ws + ROWANY_OFF);
    u64* sortbuf = (u64*)(ws + SORT_OFF);
    float4* selbox = (float4*)(ws + SELBOX_OFF);
    float* selsc   = (float*)(ws + SELSC_OFF);
    float* sellm   = (float*)(ws + SELLM_OFF);
    u64* maskp     = (u64*)(ws + MASK_OFF);
    u64* keepp     = (u64*)(ws + KEEP_OFF);

    hipMemsetAsync(d_ws, 0, MEMSET_BYTES, stream);

    int nb = 2048;
    k_hist<<<nb, 256, 0, stream>>>(conf, N, hist);
    k_scan<<<1, 64, 0, stream>>>(hist, ctr);
    k_compact<<<nb, 256, 0, stream>>>(conf, N, ctr, &ctr[0], sortbuf);
    k_sort_decode<<<1, 1024, 0, stream>>>(loc, priors, landm, sortbuf, selbox, selsc, sellm);
    k_mask<<<256, 256, 0, stream>>>(selbox, maskp, rowAny);
    k_nms<<<1, 64, 0, stream>>>(maskp, rowAny, selsc, keepp);
    k_final<<<16, 256, 0, stream>>>(selbox, selsc, sellm, keepp, out);
}

// Round 2
// 158.056 us; speedup vs baseline: 1.6751x; 1.6751x over previous
//
#include <hip/hip_runtime.h>
#include <stdint.h>

typedef unsigned long long u64;
typedef unsigned int u32;

#define CONF_T 0.9f
#define IOU_T 0.5f
#define TOPK 4096
#define SORTN 8192

// ---- workspace layout (bytes) ----
#define HIST_OFF     0          // u32[4096]   16384
#define CTR_OFF      16384      // u32[16]: [1]=thrB [2]=M
#define ROWANY_OFF   16448      // u32[4096]   16384
#define SELBOX_OFF   32832      // float4[4096] 65536
#define SELSC_OFF    98368      // float[4096]  16384
#define SELLM_OFF    114752     // float[4096*10] 163840
#define MEMSET_BYTES 278592     // zero everything above each call
#define BINSTART_OFF 278592     // u32[4096]   16384
#define BINCUR_OFF   294976     // u32[4096]   16384
#define SORT_OFF     311360     // u64[8192]   65536
#define VALIDW_OFF   376896     // u64[64]     512
#define NZW_OFF      377408     // u64[64]     512
#define INTRA_OFF    377920     // u64[4096]   32768
#define MASK_OFF     410688     // u64[4096*64] 2097152
#define KEEP_OFF     2507840    // u64[64]     512

__device__ __forceinline__ int score_bin(float s) {
    u32 b = __float_as_uint(s);
    if (b >= 0x3F800000u) return 0;
    int bin = (int)((0x3F800000u - b) >> 9);
    return bin > 4095 ? 4095 : bin;
}

// K1: histogram of candidate scores (score > 0.9)
__global__ void k_hist(const float2* __restrict__ conf, int N, u32* __restrict__ hist) {
    int stride = gridDim.x * blockDim.x;
    for (int i = blockIdx.x * blockDim.x + threadIdx.x; i < N; i += stride) {
        float s = conf[i].y;
        if (s > CONF_T) atomicAdd(&hist[score_bin(s)], 1u);
    }
}

// K2: full exclusive prefix over 4096 bins + threshold bin B + superset size M
__global__ void __launch_bounds__(256) k_scan(const u32* __restrict__ hist,
                                              u32* __restrict__ binStart,
                                              u32* __restrict__ binCur,
                                              u32* __restrict__ ctr) {
    __shared__ u32 parts[256];
    int t = threadIdx.x;
    u32 h[16];
    u32 sum = 0;
    #pragma unroll
    for (int i = 0; i < 16; i++) { h[i] = hist[t * 16 + i]; sum += h[i]; }
    parts[t] = sum;
    __syncthreads();
    for (int d = 1; d < 256; d <<= 1) {
        u32 add = (t >= d) ? parts[t - d] : 0u;
        __syncthreads();
        parts[t] += add;
        __syncthreads();
    }
    u32 incl = parts[t];
    u32 excl = incl - sum;
    u32 total = parts[255];
    u32 target = total < TOPK ? total : TOPK;
    u32 run = excl;
    #pragma unroll
    for (int i = 0; i < 16; i++) {
        binStart[t * 16 + i] = run;
        binCur[t * 16 + i] = run;
        run += h[i];
    }
    if (total == 0) {
        if (t == 0) { ctr[1] = 0xFFFFFFFFu; ctr[2] = 0u; }
        return;
    }
    if (excl < target && incl >= target) {
        u32 r2 = excl;
        for (int i = 0; i < 16; i++) {
            r2 += h[i];
            if (r2 >= target) { ctr[1] = (u32)(t * 16 + i); ctr[2] = r2; break; }
        }
    }
}

// K3: counting-sort append into per-bin segments (keys (score_bits<<32)|~idx)
__global__ void k_compact(const float2* __restrict__ conf, int N,
                          const u32* __restrict__ ctr, u32* __restrict__ binCur,
                          u64* __restrict__ sortbuf) {
    u32 B = ctr[1];
    int stride = gridDim.x * blockDim.x;
    for (int i = blockIdx.x * blockDim.x + threadIdx.x; i < N; i += stride) {
        float s = conf[i].y;
        if (s > CONF_T) {
            int bin = score_bin(s);
            if ((u32)bin <= B) {
                u32 pos = atomicAdd(&binCur[bin], 1u);
                if (pos < SORTN) {
                    sortbuf[pos] = ((u64)__float_as_uint(s) << 32) | (u64)(~(u32)i);
                }
            }
        }
    }
}

// K4: exact rank within bin (~84 compares) + decode + scatter to rank position
__global__ void __launch_bounds__(256) k_rank(
        const float4* __restrict__ loc, const float4* __restrict__ priors,
        const float* __restrict__ landm, const u64* __restrict__ sortbuf,
        const u32* __restrict__ hist, const u32* __restrict__ binStart,
        const u32* __restrict__ ctr,
        float4* __restrict__ selbox, float* __restrict__ selscore,
        float* __restrict__ sellm) {
    u32 M = ctr[2];
    if (M > SORTN) M = SORTN;
    u32 p = blockIdx.x * 256 + threadIdx.x;
    if (p >= M) return;
    u64 key = sortbuf[p];
    float sc = __uint_as_float((u32)(key >> 32));
    int bin = score_bin(sc);
    u32 st = binStart[bin];
    u32 cnt = hist[bin];
    u32 end = st + cnt;
    if (end > M) end = M;
    u32 rank = st;
    for (u32 j = st; j < end; j++) {
        rank += (sortbuf[j] > key) ? 1u : 0u;
    }
    if (rank >= TOPK) return;
    u32 idx = ~(u32)key;
    float4 L = loc[idx];
    float4 P = priors[idx];
    float cx = P.x + L.x * 0.1f * P.z;
    float cy = P.y + L.y * 0.1f * P.w;
    float wx = P.z * expf(L.z * 0.2f);
    float wy = P.w * expf(L.w * 0.2f);
    float4 bx;
    bx.x = (cx - 0.5f * wx) * 8192.f;
    bx.y = (cy - 0.5f * wy) * 8192.f;
    bx.z = (cx + 0.5f * wx) * 8192.f;
    bx.w = (cy + 0.5f * wy) * 8192.f;
    selbox[rank] = bx;
    selscore[rank] = sc;
    const float* lmr = landm + (size_t)idx * 10;
    float* lmo = sellm + (size_t)rank * 10;
    #pragma unroll
    for (int q = 0; q < 5; q++) {
        float lx = lmr[2 * q], ly = lmr[2 * q + 1];
        lmo[2 * q]     = (P.x + lx * 0.1f * P.z) * 8192.f;
        lmo[2 * q + 1] = (P.y + ly * 0.1f * P.w) * 8192.f;
    }
}

// K5: suppression bitmask matrix: mask[i][w] bit jj set iff j=w*64+jj > i and IoU(i,j) > 0.5
__global__ void __launch_bounds__(256) k_mask(const float4* __restrict__ selbox,
                                              u64* __restrict__ mask,
                                              u32* __restrict__ rowAny) {
    __shared__ float4 sb[TOPK];   // 64 KB
    int t = threadIdx.x, b = blockIdx.x;
    for (int i = t; i < TOPK; i += 256) sb[i] = selbox[i];
    __syncthreads();
    int row0 = b * 16;
    #pragma unroll
    for (int pp = 0; pp < 4; pp++) {
        int id = t + pp * 256;          // 0..1023
        int row = row0 + (id >> 6);
        int w = id & 63;
        u64 bits = 0ull;
        if (w * 64 + 63 > row) {
            float4 bi = sb[row];
            float ai = fmaxf(bi.z - bi.x, 0.f) * fmaxf(bi.w - bi.y, 0.f);
            int jbase = w * 64;
            for (int jj = 0; jj < 64; jj++) {
                int j = jbase + jj;
                if (j <= row) continue;
                float4 bj = sb[j];
                float aj = fmaxf(bj.z - bj.x, 0.f) * fmaxf(bj.w - bj.y, 0.f);
                float lx = fmaxf(bi.x, bj.x), ly = fmaxf(bi.y, bj.y);
                float rx = fminf(bi.z, bj.z), ry = fminf(bi.w, bj.w);
                float inter = fmaxf(rx - lx, 0.f) * fmaxf(ry - ly, 0.f);
                float iou = inter / (ai + aj - inter + 1e-12f);
                if (iou > IOU_T) bits |= 1ull << jj;
            }
        }
        mask[(size_t)row * 64 + w] = bits;
        if (bits) atomicOr(&rowAny[row], 1u);
    }
}

// K5b: per-group ballots + intra-group mask word gather (removes latency chain from k_nms)
__global__ void __launch_bounds__(1024) k_bitmaps(const float* __restrict__ selscore,
                                                  const u32* __restrict__ rowAny,
                                                  const u64* __restrict__ mask,
                                                  u64* __restrict__ validw,
                                                  u64* __restrict__ nzw,
                                                  u64* __restrict__ intraBuf) {
    int id = blockIdx.x * 1024 + threadIdx.x;   // 4 blocks x 1024 = 4096
    int g = id >> 6, t = id & 63;
    float s = selscore[id];
    u32 ra = rowAny[id];
    u64 vb = __ballot(s > CONF_T);
    u64 nb = __ballot(ra != 0u);
    if (t == 0) { validw[g] = vb; nzw[g] = nb; }
    intraBuf[id] = mask[(size_t)id * 64 + g];
}

// K6: serial greedy NMS reduce, one wave, register/LDS resident
__global__ void k_nms(const u64* __restrict__ mask, const u64* __restrict__ validw_arr,
                      const u64* __restrict__ nzw_arr, const u64* __restrict__ intraBuf,
                      u64* __restrict__ keepout) {
    __shared__ u64 intra_s[4096];   // 32 KB
    int t = threadIdx.x;  // 64
    for (int i = t; i < 4096; i += 64) intra_s[i] = intraBuf[i];
    u64 vw = validw_arr[t];
    u64 nzv = nzw_arr[t];
    __syncthreads();
    u64 sup = 0ull, keepw = 0ull;
    for (int g = 0; g < 64; g++) {
        u64 cur = __shfl(sup, g);
        u64 validg = __shfl(vw, g);
        u64 nzg = __shfl(nzv, g);
        u64 alive = (~cur) & validg;
        if (nzg) {
            u64 intra = intra_s[g * 64 + t];
            u64 rem = nzg;
            while (rem) {
                int bb = __ffsll((long long)rem) - 1;
                rem &= rem - 1;
                if ((alive >> bb) & 1ull) {
                    u64 rowb = __shfl(intra, bb);
                    alive &= ~rowb;
                }
            }
        }
        if (t == g) keepw = alive;
        u64 srem = alive & nzg;
        while (srem) {
            int bb = __ffsll((long long)srem) - 1;
            srem &= srem - 1;
            sup |= mask[(size_t)(g * 64 + bb) * 64 + t];
        }
    }
    keepout[t] = keepw;
}

// K7: write output rows (zeroed when not kept)
__global__ void k_final(const float4* __restrict__ selbox, const float* __restrict__ selscore,
                        const float* __restrict__ sellm, const u64* __restrict__ keep,
                        float* __restrict__ out) {
    int i = blockIdx.x * blockDim.x + threadIdx.x;
    if (i >= TOPK) return;
    bool kp = (keep[i >> 6] >> (i & 63)) & 1ull;
    float4 b = selbox[i];
    float* o = out + (size_t)i * 15;
    o[0] = kp ? b.x : 0.f;
    o[1] = kp ? b.y : 0.f;
    o[2] = kp ? b.z : 0.f;
    o[3] = kp ? b.w : 0.f;
    o[4] = kp ? selscore[i] : 0.f;
    #pragma unroll
    for (int q = 0; q < 10; q++) o[5 + q] = kp ? sellm[(size_t)i * 10 + q] : 0.f;
}

extern "C" void kernel_launch(void* const* d_in, const int* in_sizes, int n_in,
                              void* d_out, int out_size, void* d_ws, size_t ws_size,
                              hipStream_t stream) {
    const float4* loc    = (const float4*)d_in[0];
    const float2* conf   = (const float2*)d_in[1];
    const float*  landm  = (const float*)d_in[2];
    const float4* priors = (const float4*)d_in[3];
    float* out = (float*)d_out;
    int N = in_sizes[1] / 2;

    char* ws = (char*)d_ws;
    u32* hist     = (u32*)(ws + HIST_OFF);
    u32* ctr      = (u32*)(ws + CTR_OFF);
    u32* rowAny   = (u32*)(ws + ROWANY_OFF);
    float4* selbox = (float4*)(ws + SELBOX_OFF);
    float* selsc   = (float*)(ws + SELSC_OFF);
    float* sellm   = (float*)(ws + SELLM_OFF);
    u32* binStart = (u32*)(ws + BINSTART_OFF);
    u32* binCur   = (u32*)(ws + BINCUR_OFF);
    u64* sortbuf  = (u64*)(ws + SORT_OFF);
    u64* validw   = (u64*)(ws + VALIDW_OFF);
    u64* nzw      = (u64*)(ws + NZW_OFF);
    u64* intraBuf = (u64*)(ws + INTRA_OFF);
    u64* maskp    = (u64*)(ws + MASK_OFF);
    u64* keepp    = (u64*)(ws + KEEP_OFF);

    hipMemsetAsync(d_ws, 0, MEMSET_BYTES, stream);

    int nb = 2048;
    k_hist<<<nb, 256, 0, stream>>>(conf, N, hist);
    k_scan<<<1, 256, 0, stream>>>(hist, binStart, binCur, ctr);
    k_compact<<<nb, 256, 0, stream>>>(conf, N, ctr, binCur, sortbuf);
    k_rank<<<32, 256, 0, stream>>>(loc, priors, landm, sortbuf, hist, binStart, ctr,
                                   selbox, selsc, sellm);
    k_mask<<<256, 256, 0, stream>>>(selbox, maskp, rowAny);
    k_bitmaps<<<4, 1024, 0, stream>>>(selsc, rowAny, maskp, validw, nzw, intraBuf);
    k_nms<<<1, 64, 0, stream>>>(maskp, validw, nzw, intraBuf, keepp);
    k_final<<<16, 256, 0, stream>>>(selbox, selsc, sellm, keepp, out);
}